// Round 14
// baseline (106.779 us; speedup 1.0000x reference)
//
#include <hip/hip_runtime.h>

#define BB 1024
#define TT 512
#define KK 64
#define CH 8   // scan steps per chunk

typedef _Float16 f16x8 __attribute__((ext_vector_type(8)));
typedef float f32x4 __attribute__((ext_vector_type(4)));

__device__ __forceinline__ float wave_sum(float v) {
#pragma unroll
    for (int off = 1; off < 64; off <<= 1) v += __shfl_xor(v, off);
    return v;
}

__device__ __forceinline__ float wave_max(float v) {
#pragma unroll
    for (int off = 1; off < 64; off <<= 1) v = fmaxf(v, __shfl_xor(v, off));
    return v;
}

#define MFMA16(A, B, C) __builtin_amdgcn_mfma_f32_16x16x32_f16((A), (B), (C), 0, 0, 0)

// One wave per batch element; lane j owns state j. 1 wave/SIMD at grid=1024.
// The 64x64 matvec s = E.p is now 8 MFMA (4 row-blocks x 2 K-chunks of
// mfma_f32_16x16x32_f16). B operand = p replicated in all 16 cols: with the
// k=8g+e slot convention on both operands, the B-frag is a raw ds_read_b128
// of p[] at byte 16g (chunk0) / 64+16g (chunk1). E's rows are PERMUTED
// (sigma: row 16r+4g'+e' <- orig 16g'+4r+e', self-inverse bitfield swap) so
// lane j = 16g+i finds s_orig[j] in its own D-frag r=i>>2, elem e=i&3
// (C/D layout col=lane&15, row=4*(lane>>4)+elem, HW-verified). Static
// 15-cndmask select tree extracts it. In-chain pow-2 rescale as round 13.
__global__ void __launch_bounds__(64)
__attribute__((amdgpu_waves_per_eu(1, 1)))
crf_fwd(
    const float* __restrict__ logits,
    const float* __restrict__ trans,
    const int* __restrict__ gold,
    const int* __restrict__ seq_len,
    float* __restrict__ ws)
{
    __shared__ __align__(16) _Float16 plds[KK];   // p broadcast buffer (f16)
    const int b = blockIdx.x;
    const int j = threadIdx.x & 63;
    const float* lg = logits + (size_t)b * (TT * KK);
    const int* gd = gold + (size_t)b * TT;
    const int L = seq_len[b];

    const int i = j & 15;          // col within 16-lane group
    const int g = j >> 4;          // lane group (k-slot group)
    const bool sel1 = (i & 1) != 0;
    const bool sel2 = (i & 2) != 0;
    const bool sel4 = (i & 4) != 0;
    const bool sel8 = (i & 8) != 0;

    // ---- Phase A: lane-parallel first & second terms (off the scan) ----
    float af = 0.0f, asec = 0.0f;
#pragma unroll
    for (int c = 0; c < TT / 64; ++c) {
        int t = c * 64 + j;
        if (t < L) {
            int g0 = gd[t];
            af += lg[t * KK + g0];
            if (t + 1 < L) {
                int g1 = gd[t + 1];
                asec += trans[g0 * KK + g1];
            }
        }
    }

    // ---- A-fragments: 8 x f16x8 (4 row-blocks x 2 K-chunks) ----
    // Block r, lane row q=i: permuted row q of block r = orig row
    // 16*(i>>2) + 4r + (i&3). Elems e=0..7 = exp(trans[row][32c+8g+e]).
    const int baserow = ((i >> 2) << 4) + (i & 3);
    f16x8 A00, A01, A10, A11, A20, A21, A30, A31;
#define LDA(rr, cc, DST) { \
    const float* rp_ = trans + (size_t)(baserow + 4 * (rr)) * KK + 32 * (cc) + 8 * g; \
    f32x4 u0 = *(const f32x4*)rp_; f32x4 u1 = *(const f32x4*)(rp_ + 4); \
    DST[0] = (_Float16)__expf(u0.x); DST[1] = (_Float16)__expf(u0.y); \
    DST[2] = (_Float16)__expf(u0.z); DST[3] = (_Float16)__expf(u0.w); \
    DST[4] = (_Float16)__expf(u1.x); DST[5] = (_Float16)__expf(u1.y); \
    DST[6] = (_Float16)__expf(u1.z); DST[7] = (_Float16)__expf(u1.w); }
    LDA(0, 0, A00) LDA(0, 1, A01)
    LDA(1, 0, A10) LDA(1, 1, A11)
    LDA(2, 0, A20) LDA(2, 1, A21)
    LDA(3, 0, A30) LDA(3, 1, A31)
#undef LDA

    // ---- t = 0 init ----
    float a0 = lg[j];
    float mx = wave_max(a0);
    float p0 = __expf(a0 - mx);          // in (0, 1], fits f16
    plds[j] = (_Float16)p0;
    int Etot = 0;

    // ---- preload chunk 0 (t = 1..8) ----
    f32x4 nl0, nl1;
    nl0.x = lg[1 * KK + j]; nl0.y = lg[2 * KK + j];
    nl0.z = lg[3 * KK + j]; nl0.w = lg[4 * KK + j];
    nl1.x = lg[5 * KK + j]; nl1.y = lg[6 * KK + j];
    nl1.z = lg[7 * KK + j]; nl1.w = lg[8 * KK + j];

    // One recursion step: 2 B-frag reads -> 8 MFMA -> 15-cndmask select ->
    // el multiply -> in-chain pow-2 rescale -> f16 store.
#define STEP(EL) { \
    const f16x8* pb_ = (const f16x8*)plds; \
    f16x8 B0 = pb_[g]; \
    f16x8 B1 = pb_[g + 4]; \
    f32x4 D0 = {0.f, 0.f, 0.f, 0.f}, D1 = {0.f, 0.f, 0.f, 0.f}; \
    f32x4 D2 = {0.f, 0.f, 0.f, 0.f}, D3 = {0.f, 0.f, 0.f, 0.f}; \
    D0 = MFMA16(A00, B0, D0); D1 = MFMA16(A10, B0, D1); \
    D2 = MFMA16(A20, B0, D2); D3 = MFMA16(A30, B0, D3); \
    D0 = MFMA16(A01, B1, D0); D1 = MFMA16(A11, B1, D1); \
    D2 = MFMA16(A21, B1, D2); D3 = MFMA16(A31, B1, D3); \
    float t0_ = sel1 ? D0[1] : D0[0]; float t1_ = sel1 ? D0[3] : D0[2]; \
    float s0_ = sel2 ? t1_ : t0_; \
    float t2_ = sel1 ? D1[1] : D1[0]; float t3_ = sel1 ? D1[3] : D1[2]; \
    float s1_ = sel2 ? t3_ : t2_; \
    float t4_ = sel1 ? D2[1] : D2[0]; float t5_ = sel1 ? D2[3] : D2[2]; \
    float s2_ = sel2 ? t5_ : t4_; \
    float t6_ = sel1 ? D3[1] : D3[0]; float t7_ = sel1 ? D3[3] : D3[2]; \
    float s3_ = sel2 ? t7_ : t6_; \
    float sa_ = sel4 ? s1_ : s0_; float sb_ = sel4 ? s3_ : s2_; \
    float s_ = sel8 ? sb_ : sa_; \
    float pn = s_ * (EL); \
    unsigned sb = (unsigned)__builtin_amdgcn_readfirstlane((int)__float_as_uint(pn)); \
    int ee = (int)((sb >> 23) & 255u) - 127; \
    Etot += ee; \
    float scl = __uint_as_float((unsigned)((127 - ee) << 23)); \
    plds[j] = (_Float16)(pn * scl); }

    // ---- main loop: full chunks only (all CH steps strictly < L) ----
    int t0 = 1;
    for (; t0 + CH <= L; t0 += CH) {
        // keep the 8 A-frags live in VGPRs (anti-spill anchors)
        asm volatile("" : "+v"(A00), "+v"(A01), "+v"(A10), "+v"(A11),
                          "+v"(A20), "+v"(A21), "+v"(A30), "+v"(A31));

        // exp of current chunk's logits (off the critical p-chain)
        f32x4 el0, el1;
        el0.x = __expf(nl0.x); el0.y = __expf(nl0.y);
        el0.z = __expf(nl0.z); el0.w = __expf(nl0.w);
        el1.x = __expf(nl1.x); el1.y = __expf(nl1.y);
        el1.z = __expf(nl1.z); el1.w = __expf(nl1.w);

        // prefetch next chunk (consumed one full chunk later; also feeds the
        // remainder steps after the last full chunk)
        {
            int tn = t0 + CH;
            int c0 = tn + 0; c0 = (c0 > TT - 1) ? TT - 1 : c0;
            int c1 = tn + 1; c1 = (c1 > TT - 1) ? TT - 1 : c1;
            int c2 = tn + 2; c2 = (c2 > TT - 1) ? TT - 1 : c2;
            int c3 = tn + 3; c3 = (c3 > TT - 1) ? TT - 1 : c3;
            int c4 = tn + 4; c4 = (c4 > TT - 1) ? TT - 1 : c4;
            int c5 = tn + 5; c5 = (c5 > TT - 1) ? TT - 1 : c5;
            int c6 = tn + 6; c6 = (c6 > TT - 1) ? TT - 1 : c6;
            int c7 = tn + 7; c7 = (c7 > TT - 1) ? TT - 1 : c7;
            nl0.x = lg[c0 * KK + j]; nl0.y = lg[c1 * KK + j];
            nl0.z = lg[c2 * KK + j]; nl0.w = lg[c3 * KK + j];
            nl1.x = lg[c4 * KK + j]; nl1.y = lg[c5 * KK + j];
            nl1.z = lg[c6 * KK + j]; nl1.w = lg[c7 * KK + j];
        }

        STEP(el0.x) STEP(el0.y) STEP(el0.z) STEP(el0.w)
        STEP(el1.x) STEP(el1.y) STEP(el1.z) STEP(el1.w)
    }

    // ---- remainder: at most CH-1 steps, wave-uniform guards ----
    if (t0 < L) {
        f32x4 el0, el1;
        el0.x = __expf(nl0.x); el0.y = __expf(nl0.y);
        el0.z = __expf(nl0.z); el0.w = __expf(nl0.w);
        el1.x = __expf(nl1.x); el1.y = __expf(nl1.y);
        el1.z = __expf(nl1.z); el1.w = __expf(nl1.w);
        if (t0 + 0 < L) { STEP(el0.x) }
        if (t0 + 1 < L) { STEP(el0.y) }
        if (t0 + 2 < L) { STEP(el0.z) }
        if (t0 + 3 < L) { STEP(el0.w) }
        if (t0 + 4 < L) { STEP(el1.x) }
        if (t0 + 5 < L) { STEP(el1.y) }
        if (t0 + 6 < L) { STEP(el1.z) }
    }
#undef STEP

    float pfin = (float)plds[j];
    float sump = wave_sum(pfin);
    float third_b = mx + (float)Etot * 0.6931471805599453f + __logf(sump);
    float first_b = wave_sum(af);
    float second_b = wave_sum(asec);

    if (j == 0) {
        ws[b] = (third_b - first_b - second_b) * (1.0f / (float)BB);
    }
}

// Deterministic fixed-order reduction of the 1024 per-b contributions.
__global__ void crf_reduce(const float* __restrict__ ws, float* __restrict__ out) {
    int tid = threadIdx.x;  // 256 threads
    float v = ws[tid] + ws[tid + 256] + ws[tid + 512] + ws[tid + 768];
    v = wave_sum(v);
    __shared__ float sm[4];
    if ((tid & 63) == 0) sm[tid >> 6] = v;
    __syncthreads();
    if (tid == 0) out[0] = (sm[0] + sm[1]) + (sm[2] + sm[3]);
}

extern "C" void kernel_launch(void* const* d_in, const int* in_sizes, int n_in,
                              void* d_out, int out_size, void* d_ws, size_t ws_size,
                              hipStream_t stream) {
    const float* logits = (const float*)d_in[0];
    const float* trans  = (const float*)d_in[1];
    const int*   gold   = (const int*)d_in[2];
    const int*   slen   = (const int*)d_in[3];
    float* out = (float*)d_out;
    float* ws = (float*)d_ws;

    hipLaunchKernelGGL(crf_fwd, dim3(BB), dim3(64), 0, stream,
                       logits, trans, gold, slen, ws);
    hipLaunchKernelGGL(crf_reduce, dim3(1), dim3(256), 0, stream, ws, out);
}